// Round 8
// baseline (193.764 us; speedup 1.0000x reference)
//
#include <hip/hip_runtime.h>
#include <cstdint>
#include <cstddef>

#define V_SIZE 50257
#define V_PAD  50432
#define NV4    (V_PAD/4)
#define NVB    ((V_SIZE + 3) / 4)
#define D_DIM  1024
#define T_TOK  8192
#define NCHUNK 64
#define CCHUNK 128
#define NCAND  2048
#define NTILES 16
#define LOWR   32
#define SDCAP  6144
#define ESCALE 32.0f   // emb pre-scale before fp8 (power of 2; folded out in epilogue)

typedef unsigned int  uint32;
typedef unsigned short u16;
typedef unsigned char u8;
typedef unsigned long long u64;
typedef __attribute__((ext_vector_type(8))) short short8;
typedef __attribute__((ext_vector_type(4))) float f32x4;

__device__ __forceinline__ u16 f2bf(float f){
  uint32 u = __float_as_uint(f);
  return (u16)((u + 0x7FFFu + ((u >> 16) & 1u)) >> 16);
}
__device__ __forceinline__ uint32 key_of(float f){
  uint32 b = __float_as_uint(f);
  return b ^ ((uint32)((int)b >> 31) | 0x80000000u);
}
__device__ __forceinline__ float sigscale(const float* lsc){
  return 100.f / (1.f + __expf(-lsc[0])) + 1.f;
}
__device__ __forceinline__ float wred_sum(float v){
  #pragma unroll
  for (int m = 32; m >= 1; m >>= 1) v += __shfl_xor(v, m, 64);
  return v;
}
__device__ __forceinline__ float wred_max(float v){
  #pragma unroll
  for (int m = 32; m >= 1; m >>= 1) v = fmaxf(v, __shfl_xor(v, m, 64));
  return v;
}
__device__ __forceinline__ void gload_lds16(const void* g, void* l){
  __builtin_amdgcn_global_load_lds(
      (const __attribute__((address_space(1))) uint32*)g,
      (__attribute__((address_space(3))) uint32*)l, 16, 0, 0);
}
__device__ __forceinline__ void load_row16(const float* base, int lane, float* f){
  const float4* s4 = (const float4*)(base + lane * 16);
  float4 t0 = s4[0], t1 = s4[1], t2 = s4[2], t3 = s4[3];
  f[0]=t0.x; f[1]=t0.y; f[2]=t0.z;  f[3]=t0.w;
  f[4]=t1.x; f[5]=t1.y; f[6]=t1.z;  f[7]=t1.w;
  f[8]=t2.x; f[9]=t2.y; f[10]=t2.z; f[11]=t2.w;
  f[12]=t3.x; f[13]=t3.y; f[14]=t3.z; f[15]=t3.w;
}
__device__ __forceinline__ void store_bf16x16(u16* dst_base, int lane, const float* f){
  uint32 pk[8];
  #pragma unroll
  for (int i=0;i<8;++i) pk[i] = (uint32)f2bf(f[2*i]) | ((uint32)f2bf(f[2*i+1]) << 16);
  uint4* d = (uint4*)(dst_base + lane * 16);
  d[0] = make_uint4(pk[0],pk[1],pk[2],pk[3]);
  d[1] = make_uint4(pk[4],pk[5],pk[6],pk[7]);
}
__device__ __forceinline__ void store_fp8x16(u8* dst_base, int lane, const float* f, float sc){
  uint32 pk[4];
  #pragma unroll
  for (int i=0;i<4;++i){
    int w = __builtin_amdgcn_cvt_pk_fp8_f32(f[4*i]*sc,   f[4*i+1]*sc, 0, false);
    w     = __builtin_amdgcn_cvt_pk_fp8_f32(f[4*i+2]*sc, f[4*i+3]*sc, w, true);
    pk[i] = (uint32)w;
  }
  *(uint4*)(dst_base + lane * 16) = make_uint4(pk[0],pk[1],pk[2],pk[3]);
}
// fp8 fragment read address within a 64B-row LDS tile (both-sides 16B XOR swizzle)
__device__ __forceinline__ int a8(int r, int slot8){
  return r*64 + ((((slot8>>1) ^ (r&3))) << 4) + ((slot8&1) << 3);
}

// ------- fused prep: vocab (blocks [0,NVB)) + tokens (blocks [NVB,NVB+512)) ----
__global__ void __launch_bounds__(256)
prep_kernel(const float* __restrict__ emb, u8* __restrict__ emb8,
            u16* __restrict__ elow16,
            float* __restrict__ invn_f, float* __restrict__ invn_l,
            float* __restrict__ wlow,
            const float* __restrict__ h, u8* __restrict__ h8,
            u16* __restrict__ hlow16,
            float* __restrict__ invh_f, float* __restrict__ invh_l,
            float* __restrict__ hpart, float* __restrict__ out)
{
  const int bid = blockIdx.x;
  const int tid = threadIdx.x, lane = tid & 63, wid = tid >> 6;
  if (bid < NVB){
    if (bid == 0 && tid == 0) out[0] = 0.f;   // zero loss accumulator
    const int v = bid * 4 + wid;
    if (v >= V_SIZE) return;
    float f[16];
    load_row16(emb + (size_t)v * D_DIM, lane, f);
    float ss = 0.f;
    #pragma unroll
    for (int k=0;k<16;++k) ss += f[k]*f[k];
    float fullss = wred_sum(ss);
    float lowss  = wred_sum(lane < 2 ? ss : 0.f);   // lanes 0,1 own elems 0..31
    store_fp8x16(emb8 + (size_t)v * D_DIM, lane, f, ESCALE);
    if (lane < 2){
      store_bf16x16(elow16 + (size_t)v * LOWR, lane, f);
      float4* wp = (float4*)(wlow + (size_t)v * LOWR + lane * 16);
      wp[0] = make_float4(f[0], f[1], f[2],  f[3]);
      wp[1] = make_float4(f[4], f[5], f[6],  f[7]);
      wp[2] = make_float4(f[8], f[9], f[10], f[11]);
      wp[3] = make_float4(f[12],f[13],f[14], f[15]);
    }
    if (lane == 0){
      invn_f[v] = 1.f / fmaxf(sqrtf(fullss), 1e-12f);
      invn_l[v] = 1.f / fmaxf(sqrtf(lowss),  1e-12f);
    }
    return;
  }
  // token path
  const int bid2 = bid - NVB;
  const int nchunk = bid2 >> 3, sub = bid2 & 7;
  __shared__ float hm[LOWR];
  if (tid < LOWR) hm[tid] = 0.f;
  __syncthreads();
  for (int i = 0; i < 4; ++i){
    const int loc = sub*16 + wid*4 + i;
    const int tok = nchunk * CCHUNK + loc;
    float f[16];
    load_row16(h + (size_t)tok * D_DIM, lane, f);
    float ss = 0.f;
    #pragma unroll
    for (int k=0;k<16;++k) ss += f[k]*f[k];
    float fullss = wred_sum(ss);
    float lowss  = wred_sum(lane < 2 ? ss : 0.f);
    float invf = 1.f / fmaxf(sqrtf(fullss), 1e-12f);
    float invl = 1.f / fmaxf(sqrtf(lowss),  1e-12f);
    store_fp8x16(h8 + (size_t)tok * D_DIM, lane, f, 1.0f);
    if (lane < 2) store_bf16x16(hlow16 + (size_t)tok * LOWR, lane, f);
    if (lane == 0){ invh_f[tok] = invf; invh_l[tok] = invl; }
    if (lane < 2){
      #pragma unroll
      for (int k=0;k<16;++k) atomicAdd(&hm[lane*16 + k], f[k] * invl * (1.f/128.f));
    }
  }
  __syncthreads();
  if (tid < LOWR) hpart[(size_t)(nchunk*8 + sub) * LOWR + tid] = hm[tid];
}

// -------- scan: scan[n][v] = h_mean[n] . (wlow[v] * invn_l[v]) (compact read) --
__global__ void __launch_bounds__(256)
scan_kernel(const float* __restrict__ wlow, const float* __restrict__ invn_l,
            const float* __restrict__ hpart, float* __restrict__ scan)
{
  __shared__ float hm[NCHUNK * LOWR];
  for (int i = threadIdx.x; i < NCHUNK * LOWR; i += 256){
    const int nn = i >> 5, l = i & 31;
    float s = 0.f;
    #pragma unroll
    for (int p = 0; p < 8; ++p) s += hpart[(size_t)(nn*8 + p) * LOWR + l];
    hm[i] = s;
  }
  __syncthreads();
  const int v = blockIdx.x * 256 + threadIdx.x;
  if (v >= V_SIZE){
    if (v < V_PAD)
      for (int nn = 0; nn < NCHUNK; ++nn) scan[(size_t)nn * V_PAD + v] = -3.4e38f;
    return;
  }
  float w[LOWR];
  const float4* s4 = (const float4*)(wlow + (size_t)v * LOWR);
  #pragma unroll
  for (int i=0;i<8;++i){
    float4 t = s4[i];
    w[4*i]=t.x; w[4*i+1]=t.y; w[4*i+2]=t.z; w[4*i+3]=t.w;
  }
  const float inv = invn_l[v];
  #pragma unroll
  for (int i=0;i<LOWR;++i) w[i] *= inv;
  for (int nn = 0; nn < NCHUNK; ++nn){
    float d = 0.f;
    #pragma unroll
    for (int l=0;l<LOWR;++l) d += w[l] * hm[nn*LOWR + l];
    scan[(size_t)nn * V_PAD + v] = d;
  }
}

// ---- single-kernel exact top-K per chunk: 8x-privatized hist + wave-agg lists -
__global__ void __launch_bounds__(1024)
topk_all(const float* __restrict__ scan,
         const float* __restrict__ invn_f, const float* __restrict__ invn_l,
         int* __restrict__ topidx, float* __restrict__ invc_f, float* __restrict__ invc_l)
{
  const int nchunk = blockIdx.x, tid = threadIdx.x, lane = tid & 63;
  __shared__ uint32 h8v[8][2048];
  __shared__ int gt_list[2048];
  __shared__ u64 sd_list[SDCAP];
  __shared__ uint32 rh[256];
  __shared__ uint32 n_gt, n_sd, s_tb, s_cgt, s_sel, s_cum, s_pos;
  if (tid == 0){ n_gt = 0; n_sd = 0; s_pos = 0; }
  for (int i = tid; i < 8*2048; i += 1024) (&h8v[0][0])[i] = 0;
  __syncthreads();
  const float4* row = (const float4*)(scan + (size_t)nchunk * V_PAD);
  const int cp = (tid >> 6) & 7;
  for (int i = tid; i < NV4; i += 1024){
    float4 x = row[i];
    atomicAdd(&h8v[cp][key_of(x.x) >> 21], 1u);
    atomicAdd(&h8v[cp][key_of(x.y) >> 21], 1u);
    atomicAdd(&h8v[cp][key_of(x.z) >> 21], 1u);
    atomicAdd(&h8v[cp][key_of(x.w) >> 21], 1u);
  }
  __syncthreads();
  for (int i = tid; i < 2048; i += 1024){
    uint32 s = h8v[0][i];
    #pragma unroll
    for (int c = 1; c < 8; ++c) s += h8v[c][i];
    h8v[0][i] = s;
  }
  __syncthreads();
  if (tid < 64){
    uint32 c = 0;
    #pragma unroll 8
    for (int k = 0; k < 32; ++k) c += h8v[0][lane*32 + k];
    uint32 s = c;
    #pragma unroll
    for (int off = 1; off < 64; off <<= 1){
      uint32 t = __shfl_down(s, off, 64);
      if (lane + off < 64) s += t;
    }
    u64 m1 = __ballot(s >= NCAND);
    const int g = 63 - __builtin_clzll(m1);
    const uint32 cum = (g < 63) ? __shfl(s, g + 1, 64) : 0u;
    uint32 s2 = (lane < 32) ? h8v[0][g*32 + lane] : 0u;
    #pragma unroll
    for (int off = 1; off < 32; off <<= 1){
      uint32 t = __shfl_down(s2, off, 64);
      if (lane + off < 32) s2 += t;
    }
    u64 m2 = __ballot((lane < 32) && (cum + s2 >= NCAND));
    const int j = 63 - __builtin_clzll(m2);
    const uint32 cgt = cum + ((j < 31) ? __shfl(s2, j + 1, 64) : 0u);
    if (lane == 0){ s_tb = (uint32)(g*32 + j); s_cgt = cgt; }
  }
  __syncthreads();
  const uint32 tb = s_tb, cgt = s_cgt;
  for (int i = tid; i < NV4; i += 1024){
    float4 x = row[i];
    const int vbase = i * 4;
    float vals[4] = {x.x, x.y, x.z, x.w};
    #pragma unroll
    for (int c = 0; c < 4; ++c){
      uint32 u = key_of(vals[c]);
      uint32 b = u >> 21;
      const int v = vbase + c;
      const bool ok = (v < V_SIZE) && (b >= tb);
      const bool is_gt = ok && (b > tb);
      const bool is_sd = ok && (b == tb);
      const u64 mg = __ballot(is_gt);
      if (mg){
        const int ldr = (int)__builtin_ctzll(mg);
        uint32 base = 0;
        if (lane == ldr) base = atomicAdd(&n_gt, (uint32)__popcll(mg));
        base = __shfl(base, ldr, 64);
        if (is_gt){
          uint32 p = base + (uint32)__popcll(mg & ((1ull << lane) - 1ull));
          if (p < 2048u) gt_list[p] = v;
        }
      }
      const u64 ms = __ballot(is_sd);
      if (ms){
        const int ldr = (int)__builtin_ctzll(ms);
        uint32 base = 0;
        if (lane == ldr) base = atomicAdd(&n_sd, (uint32)__popcll(ms));
        base = __shfl(base, ldr, 64);
        if (is_sd){
          uint32 p = base + (uint32)__popcll(ms & ((1ull << lane) - 1ull));
          if (p < (uint32)SDCAP) sd_list[p] = ((u64)(~u) << 32) | (uint32)v;
        }
      }
    }
  }
  __syncthreads();
  const uint32 ng = n_gt < 2048u ? n_gt : 2048u;
  for (uint32 i = tid; i < ng; i += 1024){
    const int v = gt_list[i];
    const int o = nchunk * NCAND + (int)i;
    topidx[o] = v; invc_f[o] = invn_f[v]; invc_l[o] = invn_l[v];
  }
  const int n = (int)(n_sd < (uint32)SDCAP ? n_sd : (uint32)SDCAP);
  uint32 r = NCAND - cgt; if ((int)r > n) r = (uint32)n;
  u64 pref = sd_list[0] & 0xFF00000000000000ull;
  uint32 rem = r;
  const int bytes6[6] = {6,5,4,2,1,0};
  for (int bi = 0; bi < 6; ++bi){
    const int by = bytes6[bi];
    if (tid < 256) rh[tid] = 0;
    __syncthreads();
    const u64 pmask = (~0ull) << ((by+1)*8);
    for (int i = tid; i < n; i += 1024){
      u64 x = sd_list[i];
      if ((x & pmask) == pref) atomicAdd(&rh[(uint32)(x >> (by*8)) & 255u], 1u);
    }
    __syncthreads();
    if (tid < 64){
      const uint32 b0 = rh[lane*4], b1 = rh[lane*4+1], b2 = rh[lane*4+2], b3 = rh[lane*4+3];
      uint32 ps = b0 + b1 + b2 + b3;
      #pragma unroll
      for (int off = 1; off < 64; off <<= 1){
        uint32 t = __shfl_up(ps, off, 64);
        if (lane >= off) ps += t;
      }
      const u64 mm = __ballot(ps >= rem);
      const int gl = (int)__builtin_ctzll(mm);
      const uint32 before = (gl > 0) ? __shfl(ps, gl-1, 64) : 0u;
      if (lane == gl){
        uint32 cum = before; uint32 bsel = (uint32)gl * 4;
        if (cum + b0 < rem){ cum += b0; bsel++;
          if (cum + b1 < rem){ cum += b1; bsel++;
            if (cum + b2 < rem){ cum += b2; bsel++; } } }
        s_sel = bsel; s_cum = cum;
      }
    }
    __syncthreads();
    pref |= ((u64)s_sel) << (by*8);
    rem -= s_cum;
    __syncthreads();
  }
  for (int i = tid; i < n; i += 1024){
    u64 x = sd_list[i];
    if (x <= pref){
      uint32 p = atomicAdd(&s_pos, 1u);
      const int v = (int)(uint32)x;
      const int o = nchunk * NCAND + (int)(cgt + p);
      topidx[o] = v; invc_f[o] = invn_f[v]; invc_l[o] = invn_l[v];
    }
  }
}

// ------- fused GEMM: fp8 main (2-phase double-buffered) + aux bf16 (K=32) ------
// 2-phase pipeline (T3 minimum recipe): issue STAGE(t+1) into the alternate
// buffer BEFORE computing tile t; the end-of-step __syncthreads (vmcnt drain)
// then lands AFTER the MFMAs covered the load latency. Aux staging rides the
// pipeline as step NSTEP.
__global__ void __launch_bounds__(256)
gemm_fused(const u8* __restrict__ h8, const u8* __restrict__ emb8,
           const u16* __restrict__ hlow16, const u16* __restrict__ elow16,
           const int* __restrict__ topidx,
           const float* __restrict__ invh_f, const float* __restrict__ invc_f,
           const float* __restrict__ invh_l, const float* __restrict__ invc_l,
           const int* __restrict__ tgts, const float* __restrict__ lsc,
           float* __restrict__ pm, float* __restrict__ pa)
{
  constexpr int NSTEP = 16;   // 1024 / 64
  const int id = blockIdx.x;
  const int s_ = id >> 3;
  const int ntile = s_ & 15;
  const int nchunk = ((s_ >> 4) << 3) | (id & 7);
  const int tid = threadIdx.x, lane = tid & 63, wid = tid >> 6;
  const int wm = wid >> 1, wn = wid & 1;
  const int fq = lane >> 4, fr = lane & 15;

  __shared__ u8 As[2][CCHUNK * 64];   // 2 x 8 KB
  __shared__ u8 Bs[2][CCHUNK * 64];
  __shared__ float s_invh[CCHUNK], s_invc[CCHUNK];
  __shared__ float s_invhl[CCHUNK], s_invcl[CCHUNK];
  __shared__ int   s_tgt[CCHUNK], s_idx[CCHUNK];

  if (tid < CCHUNK){
    s_invh[tid]  = invh_f[nchunk * CCHUNK + tid];
    s_invhl[tid] = invh_l[nchunk * CCHUNK + tid];
    s_tgt[tid]   = tgts[nchunk * CCHUNK + tid];
    int o = nchunk * NCAND + ntile * CCHUNK + tid;
    s_idx[tid]   = topidx[o];
    s_invc[tid]  = invc_f[o];
    s_invcl[tid] = invc_l[o];
  }

  // staging geometry (64B rows): 16 rows per call, 2 calls per wave per matrix
  const int rl = lane >> 2;
  const int cbyte = ((lane & 3) ^ (rl & 3)) * 16;   // pre-swizzled source slot
  const char* aptr[2];
  const char* bptr[2];
  const char* alptr[2];
  const char* blptr[2];
  #pragma unroll
  for (int s = 0; s < 2; ++s){
    int row = wid * 32 + s * 16 + rl;
    aptr[s] = (const char*)h8 + ((size_t)(nchunk * CCHUNK + row)) * D_DIM + cbyte;
    int cidx = topidx[nchunk * NCAND + ntile * CCHUNK + row];
    bptr[s] = (const char*)emb8 + (size_t)cidx * D_DIM + cbyte;
    alptr[s] = (const char*)hlow16 + ((size_t)(nchunk * CCHUNK + row)) * (LOWR*2) + cbyte;
    blptr[s] = (const char*)elow16 + (size_t)cidx * (LOWR*2) + cbyte;
  }
  const int ldst = (wid*32 + rl) * 64;   // linear LDS dest offset (per s: +16*64)

  f32x4 acc[4][4];
  #pragma unroll
  for (int m=0;m<4;++m)
    #pragma unroll
    for (int q=0;q<4;++q)
      acc[m][q] = (f32x4){0.f,0.f,0.f,0.f};

  // prologue: stage step 0 into buf 0
  #pragma unroll
  for (int s = 0; s < 2; ++s){
    gload_lds16(aptr[s], (void*)&As[0][ldst + s*16*64]);
    gload_lds16(bptr[s], (void*)&Bs[0][ldst + s*16*64]);
  }
  __syncthreads();

  int cur = 0;
  for (int st = 0; st < NSTEP; ++st){
    // prefetch next step (or aux tables) into the alternate buffer
    if (st + 1 < NSTEP){
      const int koff = (st + 1) * 64;
      #pragma unroll
      for (int s = 0; s < 2; ++s){
        gload_lds16(aptr[s] + koff, (void*)&As[cur^1][ldst + s*16*64]);
        gload_lds16(bptr[s] + koff, (void*)&Bs[cur^1][ldst + s*16*64]);
      }
    } else {
      #pragma unroll
      for (int s = 0; s < 2; ++s){
        gload_lds16(alptr[s], (void*)&As[cur^1][ldst + s*16*64]);
        gload_lds16(blptr[s], (void*)&Bs[cur^1][ldst + s*16*64]);
      }
    }
    // compute current step
    #pragma unroll
    for (int kk = 0; kk < 2; ++kk){
      long af[4], bf[4];
      #pragma unroll
      for (int m=0;m<4;++m)
        af[m] = *(const long*)&As[cur][a8(wm*64 + m*16 + fr, kk*4 + fq)];
      #pragma unroll
      for (int q=0;q<4;++q)
        bf[q] = *(const long*)&Bs[cur][a8(wn*64 + q*16 + fr, kk*4 + fq)];
      #pragma unroll
      for (int m=0;m<4;++m)
        #pragma unroll
        for (int q=0;q<4;++q)
          acc[m][q] = __builtin_amdgcn_mfma_f32_16x16x32_fp8_fp8(af[m], bf[q], acc[m][q], 0, 0, 0);
    }
    __syncthreads();   // drains prefetch (overlapped with MFMAs above)
    cur ^= 1;
  }
  // aux tables now staged + drained in buf[cur]

  const float scale = sigscale(lsc);
  const float scm = scale * (1.0f / ESCALE);   // undo emb pre-scale (main only)
  const float NEG = -__builtin_huge_valf();

  // main epilogue -> pm
  #pragma unroll
  for (int m=0;m<4;++m){
    #pragma unroll
    for (int j=0;j<4;++j){
      const int c = wm*64 + m*16 + fq*4 + j;
      const float ihs = s_invh[c] * scm;
      const int tg = s_tgt[c];
      float vals[4];
      #pragma unroll
      for (int q=0;q<4;++q){
        const int kl = wn*64 + q*16 + fr;
        float lg = acc[m][q][j] * ihs * s_invc[kl];
        vals[q] = (s_idx[kl] == tg) ? NEG : lg;
      }
      float lmax = fmaxf(fmaxf(vals[0], vals[1]), fmaxf(vals[2], vals[3]));
      #pragma unroll
      for (int ms=1; ms<16; ms<<=1) lmax = fmaxf(lmax, __shfl_xor(lmax, ms, 64));
      float se = 0.f;
      #pragma unroll
      for (int q=0;q<4;++q) se += __expf(vals[q] - lmax);
      #pragma unroll
      for (int ms=1; ms<16; ms<<=1) se += __shfl_xor(se, ms, 64);
      if (fr == 0){
        size_t pos = ((size_t)((nchunk*NTILES + ntile)*2 + wn) * CCHUNK + c) * 2;
        pm[pos]   = lmax;
        pm[pos+1] = se;
      }
    }
  }

  // aux compute (bf16): one MFMA per fragment pair; 64B rows, 16B slot = fq
  f32x4 acc2[4][4];
  {
    short8 afa[4], bfa[4];
    #pragma unroll
    for (int m=0;m<4;++m){
      const int r = wm*64 + m*16 + fr;
      afa[m] = *(const short8*)&As[cur][r*64 + ((fq ^ (r & 3)) << 4)];
    }
    #pragma unroll
    for (int q=0;q<4;++q){
      const int r = wn*64 + q*16 + fr;
      bfa[q] = *(const short8*)&Bs[cur][r*64 + ((fq ^ (r & 3)) << 4)];
    }
    #pragma unroll
    for (int m=0;m<4;++m)
      #pragma unroll
      for (int q=0;q<4;++q)
        acc2[m][q] = __builtin_amdgcn_mfma_f32_16x16x32_bf16(
            afa[m], bfa[q], (f32x4){0.f,0.f,0.f,0.f}, 0, 0, 0);
  }

  // aux epilogue -> pa
  #pragma unroll
  for (int m=0;m<4;++m){
    #pragma unroll
    for (int j=0;j<4;++j){
      const int c = wm*64 + m*16 + fq*4 + j;
      const float ihs = s_invhl[c] * scale;
      const int tg = s_tgt[c];
      float vals[4];
      #pragma unroll
      for (int q=0;q<4;++q){
        const int kl = wn*64 + q*16 + fr;
        float lg = acc2[m][q][j] * ihs * s_invcl[kl];
        vals[q] = (s_idx[kl] == tg) ? NEG : lg;
      }
      float lmax = fmaxf(fmaxf(vals[0], vals[1]), fmaxf(vals[2], vals[3]));
      #pragma unroll
      for (int ms=1; ms<16; ms<<=1) lmax = fmaxf(lmax, __shfl_xor(lmax, ms, 64));
      float se = 0.f;
      #pragma unroll
      for (int q=0;q<4;++q) se += __expf(vals[q] - lmax);
      #pragma unroll
      for (int ms=1; ms<16; ms<<=1) se += __shfl_xor(se, ms, 64);
      if (fr == 0){
        size_t pos = ((size_t)((nchunk*NTILES + ntile)*2 + wn) * CCHUNK + c) * 2;
        pa[pos]   = lmax;
        pa[pos+1] = se;
      }
    }
  }
}

// ---- merge partials + fp32 target term -> scalar loss -------------------------
__global__ void __launch_bounds__(256)
merge_loss(const float* __restrict__ h, const float* __restrict__ emb,
           const int* __restrict__ tgts,
           const float* __restrict__ invh_f, const float* __restrict__ invh_l,
           const float* __restrict__ invn_f, const float* __restrict__ invn_l,
           const float* __restrict__ pm, const float* __restrict__ pa,
           const float* __restrict__ lsc, float* __restrict__ out)
{
  const int nchunk = blockIdx.x >> 2, quarter = blockIdx.x & 3;
  const int tid = threadIdx.x, lane = tid & 63, wid = tid >> 6;
  const float scale = sigscale(lsc);
  const float NEG = -__builtin_huge_valf();
  float wacc = 0.f;
  for (int i = 0; i < 8; ++i){
    const int loc = quarter*32 + wid*8 + i;
    const int tok = nchunk * CCHUNK + loc;
    const int t = tgts[tok];
    float hf[16], ef[16];
    load_row16(h + (size_t)tok * D_DIM, lane, hf);
    load_row16(emb + (size_t)t * D_DIM, lane, ef);
    float part = 0.f;
    #pragma unroll
    for (int k=0;k<16;++k) part += hf[k]*ef[k];
    float dfull = wred_sum(part);
    float dlow  = wred_sum(lane < 2 ? part : 0.f);
    float tful = dfull * invh_f[tok] * invn_f[t] * scale;
    float tlow = dlow  * invh_l[tok] * invn_l[t] * scale;

    float mi = NEG, si = 0.f, mia = NEG, sia = 0.f;
    if (lane < 32){
      size_t q = ((size_t)(nchunk*32 + lane) * CCHUNK + loc) * 2;
      mi  = pm[q]; si  = pm[q+1];
      mia = pa[q]; sia = pa[q+1];
    }
    float M  = wred_max(mi);
    float S  = wred_sum(lane < 32 ? si * __expf(mi - M) : 0.f);
    float M2 = fmaxf(M, tful);
    float lmain = __logf(S * __expf(M - M2) + __expf(tful - M2)) + M2 - tful;
    float Ma  = wred_max(mia);
    float Sa  = wred_sum(lane < 32 ? sia * __expf(mia - Ma) : 0.f);
    float M2a = fmaxf(Ma, tlow);
    float laux = __logf(Sa * __expf(Ma - M2a) + __expf(tlow - M2a)) + M2a - tlow;
    wacc += lmain + 0.2f * laux;
  }
  __shared__ float ws4[4];
  if (lane == 0) ws4[wid] = wacc;
  __syncthreads();
  if (tid == 0) atomicAdd(out, (ws4[0]+ws4[1]+ws4[2]+ws4[3]) * (1.f / (float)T_TOK));
}

// ---------------- host ---------------------------------------------------------
extern "C" void kernel_launch(void* const* d_in, const int* in_sizes, int n_in,
                              void* d_out, int out_size, void* d_ws, size_t ws_size,
                              hipStream_t stream)
{
  (void)in_sizes; (void)n_in; (void)out_size; (void)ws_size;
  const float* h   = (const float*)d_in[0];
  const float* emb = (const float*)d_in[1];
  const float* lsc = (const float*)d_in[2];
  const int*   tgt = (const int*)d_in[3];
  float* out = (float*)d_out;

  uint8_t* p = (uint8_t*)d_ws;
  auto carve = [&](size_t n)->uint8_t*{
    uint8_t* r = p; p += (n + 255) & ~(size_t)255; return r;
  };
  u8*    emb8   = (u8*)   carve((size_t)V_SIZE * D_DIM);
  u16*   elow16 = (u16*)  carve((size_t)V_SIZE * LOWR * 2);
  float* invn_f = (float*)carve((size_t)V_SIZE * 4);
  float* invn_l = (float*)carve((size_t)V_SIZE * 4);
  float* wlow   = (float*)carve((size_t)V_SIZE * LOWR * 4);
  u8*    h8     = (u8*)   carve((size_t)T_TOK * D_DIM);
  u16*   hlow16 = (u16*)  carve((size_t)T_TOK * LOWR * 2);
  float* invh_f = (float*)carve((size_t)T_TOK * 4);
  float* invh_l = (float*)carve((size_t)T_TOK * 4);
  float* hpart  = (float*)carve((size_t)NCHUNK * 8 * LOWR * 4);
  float* scan   = (float*)carve((size_t)NCHUNK * V_PAD * 4);
  int*   topidx = (int*)  carve((size_t)NCHUNK * NCAND * 4);
  float* invc_f = (float*)carve((size_t)NCHUNK * NCAND * 4);
  float* invc_l = (float*)carve((size_t)NCHUNK * NCAND * 4);
  float* pm     = (float*)carve((size_t)NCHUNK * 32 * CCHUNK * 2 * 4);
  float* pa     = (float*)carve((size_t)NCHUNK * 32 * CCHUNK * 2 * 4);

  prep_kernel<<<dim3(NVB + NCHUNK*8), dim3(256), 0, stream>>>(
      emb, emb8, elow16, invn_f, invn_l, wlow, h, h8, hlow16, invh_f, invh_l, hpart, out);
  scan_kernel<<<dim3(V_PAD / 256), dim3(256), 0, stream>>>(wlow, invn_l, hpart, scan);
  topk_all<<<dim3(NCHUNK), dim3(1024), 0, stream>>>(
      scan, invn_f, invn_l, topidx, invc_f, invc_l);
  gemm_fused<<<dim3(NTILES * NCHUNK), dim3(256), 0, stream>>>(
      h8, emb8, hlow16, elow16, topidx, invh_f, invc_f, invh_l, invc_l, tgt, lsc, pm, pa);
  merge_loss<<<dim3(NCHUNK * 4), dim3(256), 0, stream>>>(
      h, emb, tgt, invh_f, invh_l, invn_f, invn_l, pm, pa, lsc, out);
}

// Round 9
// 192.656 us; speedup vs baseline: 1.0058x; 1.0058x over previous
//
#include <hip/hip_runtime.h>
#include <cstdint>
#include <cstddef>

#define V_SIZE 50257
#define V_PAD  50432
#define NV4    (V_PAD/4)
#define NVB    ((V_SIZE + 3) / 4)
#define D_DIM  1024
#define T_TOK  8192
#define NCHUNK 64
#define CCHUNK 128
#define NCAND  2048
#define LOWR   32
#define SDCAP  6144
#define ESCALE 32.0f   // emb pre-scale before fp8 (power of 2; folded out in epilogue)

typedef unsigned int  uint32;
typedef unsigned short u16;
typedef unsigned char u8;
typedef unsigned long long u64;
typedef __attribute__((ext_vector_type(8))) short short8;
typedef __attribute__((ext_vector_type(4))) float f32x4;

__device__ __forceinline__ u16 f2bf(float f){
  uint32 u = __float_as_uint(f);
  return (u16)((u + 0x7FFFu + ((u >> 16) & 1u)) >> 16);
}
__device__ __forceinline__ uint32 key_of(float f){
  uint32 b = __float_as_uint(f);
  return b ^ ((uint32)((int)b >> 31) | 0x80000000u);
}
__device__ __forceinline__ float sigscale(const float* lsc){
  return 100.f / (1.f + __expf(-lsc[0])) + 1.f;
}
__device__ __forceinline__ float wred_sum(float v){
  #pragma unroll
  for (int m = 32; m >= 1; m >>= 1) v += __shfl_xor(v, m, 64);
  return v;
}
__device__ __forceinline__ float wred_max(float v){
  #pragma unroll
  for (int m = 32; m >= 1; m >>= 1) v = fmaxf(v, __shfl_xor(v, m, 64));
  return v;
}
__device__ __forceinline__ void gload_lds16(const void* g, void* l){
  __builtin_amdgcn_global_load_lds(
      (const __attribute__((address_space(1))) uint32*)g,
      (__attribute__((address_space(3))) uint32*)l, 16, 0, 0);
}
__device__ __forceinline__ void load_row16(const float* base, int lane, float* f){
  const float4* s4 = (const float4*)(base + lane * 16);
  float4 t0 = s4[0], t1 = s4[1], t2 = s4[2], t3 = s4[3];
  f[0]=t0.x; f[1]=t0.y; f[2]=t0.z;  f[3]=t0.w;
  f[4]=t1.x; f[5]=t1.y; f[6]=t1.z;  f[7]=t1.w;
  f[8]=t2.x; f[9]=t2.y; f[10]=t2.z; f[11]=t2.w;
  f[12]=t3.x; f[13]=t3.y; f[14]=t3.z; f[15]=t3.w;
}
__device__ __forceinline__ void store_bf16x16(u16* dst_base, int lane, const float* f){
  uint32 pk[8];
  #pragma unroll
  for (int i=0;i<8;++i) pk[i] = (uint32)f2bf(f[2*i]) | ((uint32)f2bf(f[2*i+1]) << 16);
  uint4* d = (uint4*)(dst_base + lane * 16);
  d[0] = make_uint4(pk[0],pk[1],pk[2],pk[3]);
  d[1] = make_uint4(pk[4],pk[5],pk[6],pk[7]);
}
__device__ __forceinline__ void store_fp8x16(u8* dst_base, int lane, const float* f, float sc){
  uint32 pk[4];
  #pragma unroll
  for (int i=0;i<4;++i){
    int w = __builtin_amdgcn_cvt_pk_fp8_f32(f[4*i]*sc,   f[4*i+1]*sc, 0, false);
    w     = __builtin_amdgcn_cvt_pk_fp8_f32(f[4*i+2]*sc, f[4*i+3]*sc, w, true);
    pk[i] = (uint32)w;
  }
  *(uint4*)(dst_base + lane * 16) = make_uint4(pk[0],pk[1],pk[2],pk[3]);
}
// fp8 fragment read address within a 64B-row LDS tile (both-sides 16B XOR swizzle)
__device__ __forceinline__ int a8(int r, int slot8){
  return r*64 + ((((slot8>>1) ^ (r&3))) << 4) + ((slot8&1) << 3);
}

// ------- fused prep: vocab (blocks [0,NVB)) + tokens (blocks [NVB,NVB+512)) ----
__global__ void __launch_bounds__(256)
prep_kernel(const float* __restrict__ emb, u8* __restrict__ emb8,
            u16* __restrict__ elow16,
            float* __restrict__ invn_f, float* __restrict__ invn_l,
            float* __restrict__ wlow,
            const float* __restrict__ h, u8* __restrict__ h8,
            u16* __restrict__ hlow16,
            float* __restrict__ invh_f, float* __restrict__ invh_l,
            float* __restrict__ hpart, float* __restrict__ out)
{
  const int bid = blockIdx.x;
  const int tid = threadIdx.x, lane = tid & 63, wid = tid >> 6;
  if (bid < NVB){
    if (bid == 0 && tid == 0) out[0] = 0.f;   // zero loss accumulator
    const int v = bid * 4 + wid;
    if (v >= V_SIZE) return;
    float f[16];
    load_row16(emb + (size_t)v * D_DIM, lane, f);
    float ss = 0.f;
    #pragma unroll
    for (int k=0;k<16;++k) ss += f[k]*f[k];
    float fullss = wred_sum(ss);
    float lowss  = wred_sum(lane < 2 ? ss : 0.f);   // lanes 0,1 own elems 0..31
    store_fp8x16(emb8 + (size_t)v * D_DIM, lane, f, ESCALE);
    if (lane < 2){
      store_bf16x16(elow16 + (size_t)v * LOWR, lane, f);
      float4* wp = (float4*)(wlow + (size_t)v * LOWR + lane * 16);
      wp[0] = make_float4(f[0], f[1], f[2],  f[3]);
      wp[1] = make_float4(f[4], f[5], f[6],  f[7]);
      wp[2] = make_float4(f[8], f[9], f[10], f[11]);
      wp[3] = make_float4(f[12],f[13],f[14], f[15]);
    }
    if (lane == 0){
      invn_f[v] = 1.f / fmaxf(sqrtf(fullss), 1e-12f);
      invn_l[v] = 1.f / fmaxf(sqrtf(lowss),  1e-12f);
    }
    return;
  }
  // token path
  const int bid2 = bid - NVB;
  const int nchunk = bid2 >> 3, sub = bid2 & 7;
  __shared__ float hm[LOWR];
  if (tid < LOWR) hm[tid] = 0.f;
  __syncthreads();
  for (int i = 0; i < 4; ++i){
    const int loc = sub*16 + wid*4 + i;
    const int tok = nchunk * CCHUNK + loc;
    float f[16];
    load_row16(h + (size_t)tok * D_DIM, lane, f);
    float ss = 0.f;
    #pragma unroll
    for (int k=0;k<16;++k) ss += f[k]*f[k];
    float fullss = wred_sum(ss);
    float lowss  = wred_sum(lane < 2 ? ss : 0.f);
    float invf = 1.f / fmaxf(sqrtf(fullss), 1e-12f);
    float invl = 1.f / fmaxf(sqrtf(lowss),  1e-12f);
    store_fp8x16(h8 + (size_t)tok * D_DIM, lane, f, 1.0f);
    if (lane < 2) store_bf16x16(hlow16 + (size_t)tok * LOWR, lane, f);
    if (lane == 0){ invh_f[tok] = invf; invh_l[tok] = invl; }
    if (lane < 2){
      #pragma unroll
      for (int k=0;k<16;++k) atomicAdd(&hm[lane*16 + k], f[k] * invl * (1.f/128.f));
    }
  }
  __syncthreads();
  if (tid < LOWR) hpart[(size_t)(nchunk*8 + sub) * LOWR + tid] = hm[tid];
}

// -------- scan: scan[n][v] = h_mean[n] . (wlow[v] * invn_l[v]) (compact read) --
__global__ void __launch_bounds__(256)
scan_kernel(const float* __restrict__ wlow, const float* __restrict__ invn_l,
            const float* __restrict__ hpart, float* __restrict__ scan)
{
  __shared__ float hm[NCHUNK * LOWR];
  for (int i = threadIdx.x; i < NCHUNK * LOWR; i += 256){
    const int nn = i >> 5, l = i & 31;
    float s = 0.f;
    #pragma unroll
    for (int p = 0; p < 8; ++p) s += hpart[(size_t)(nn*8 + p) * LOWR + l];
    hm[i] = s;
  }
  __syncthreads();
  const int v = blockIdx.x * 256 + threadIdx.x;
  if (v >= V_SIZE){
    if (v < V_PAD)
      for (int nn = 0; nn < NCHUNK; ++nn) scan[(size_t)nn * V_PAD + v] = -3.4e38f;
    return;
  }
  float w[LOWR];
  const float4* s4 = (const float4*)(wlow + (size_t)v * LOWR);
  #pragma unroll
  for (int i=0;i<8;++i){
    float4 t = s4[i];
    w[4*i]=t.x; w[4*i+1]=t.y; w[4*i+2]=t.z; w[4*i+3]=t.w;
  }
  const float inv = invn_l[v];
  #pragma unroll
  for (int i=0;i<LOWR;++i) w[i] *= inv;
  for (int nn = 0; nn < NCHUNK; ++nn){
    float d = 0.f;
    #pragma unroll
    for (int l=0;l<LOWR;++l) d += w[l] * hm[nn*LOWR + l];
    scan[(size_t)nn * V_PAD + v] = d;
  }
}

// ---- single-kernel exact top-K per chunk: 8x-privatized hist + wave-agg lists -
__global__ void __launch_bounds__(1024)
topk_all(const float* __restrict__ scan,
         const float* __restrict__ invn_f, const float* __restrict__ invn_l,
         int* __restrict__ topidx, float* __restrict__ invc_f, float* __restrict__ invc_l)
{
  const int nchunk = blockIdx.x, tid = threadIdx.x, lane = tid & 63;
  __shared__ uint32 h8v[8][2048];
  __shared__ int gt_list[2048];
  __shared__ u64 sd_list[SDCAP];
  __shared__ uint32 rh[256];
  __shared__ uint32 n_gt, n_sd, s_tb, s_cgt, s_sel, s_cum, s_pos;
  if (tid == 0){ n_gt = 0; n_sd = 0; s_pos = 0; }
  for (int i = tid; i < 8*2048; i += 1024) (&h8v[0][0])[i] = 0;
  __syncthreads();
  const float4* row = (const float4*)(scan + (size_t)nchunk * V_PAD);
  const int cp = (tid >> 6) & 7;
  for (int i = tid; i < NV4; i += 1024){
    float4 x = row[i];
    atomicAdd(&h8v[cp][key_of(x.x) >> 21], 1u);
    atomicAdd(&h8v[cp][key_of(x.y) >> 21], 1u);
    atomicAdd(&h8v[cp][key_of(x.z) >> 21], 1u);
    atomicAdd(&h8v[cp][key_of(x.w) >> 21], 1u);
  }
  __syncthreads();
  for (int i = tid; i < 2048; i += 1024){
    uint32 s = h8v[0][i];
    #pragma unroll
    for (int c = 1; c < 8; ++c) s += h8v[c][i];
    h8v[0][i] = s;
  }
  __syncthreads();
  if (tid < 64){
    uint32 c = 0;
    #pragma unroll 8
    for (int k = 0; k < 32; ++k) c += h8v[0][lane*32 + k];
    uint32 s = c;
    #pragma unroll
    for (int off = 1; off < 64; off <<= 1){
      uint32 t = __shfl_down(s, off, 64);
      if (lane + off < 64) s += t;
    }
    u64 m1 = __ballot(s >= NCAND);
    const int g = 63 - __builtin_clzll(m1);
    const uint32 cum = (g < 63) ? __shfl(s, g + 1, 64) : 0u;
    uint32 s2 = (lane < 32) ? h8v[0][g*32 + lane] : 0u;
    #pragma unroll
    for (int off = 1; off < 32; off <<= 1){
      uint32 t = __shfl_down(s2, off, 64);
      if (lane + off < 32) s2 += t;
    }
    u64 m2 = __ballot((lane < 32) && (cum + s2 >= NCAND));
    const int j = 63 - __builtin_clzll(m2);
    const uint32 cgt = cum + ((j < 31) ? __shfl(s2, j + 1, 64) : 0u);
    if (lane == 0){ s_tb = (uint32)(g*32 + j); s_cgt = cgt; }
  }
  __syncthreads();
  const uint32 tb = s_tb, cgt = s_cgt;
  for (int i = tid; i < NV4; i += 1024){
    float4 x = row[i];
    const int vbase = i * 4;
    float vals[4] = {x.x, x.y, x.z, x.w};
    #pragma unroll
    for (int c = 0; c < 4; ++c){
      uint32 u = key_of(vals[c]);
      uint32 b = u >> 21;
      const int v = vbase + c;
      const bool ok = (v < V_SIZE) && (b >= tb);
      const bool is_gt = ok && (b > tb);
      const bool is_sd = ok && (b == tb);
      const u64 mg = __ballot(is_gt);
      if (mg){
        const int ldr = (int)__builtin_ctzll(mg);
        uint32 base = 0;
        if (lane == ldr) base = atomicAdd(&n_gt, (uint32)__popcll(mg));
        base = __shfl(base, ldr, 64);
        if (is_gt){
          uint32 p = base + (uint32)__popcll(mg & ((1ull << lane) - 1ull));
          if (p < 2048u) gt_list[p] = v;
        }
      }
      const u64 ms = __ballot(is_sd);
      if (ms){
        const int ldr = (int)__builtin_ctzll(ms);
        uint32 base = 0;
        if (lane == ldr) base = atomicAdd(&n_sd, (uint32)__popcll(ms));
        base = __shfl(base, ldr, 64);
        if (is_sd){
          uint32 p = base + (uint32)__popcll(ms & ((1ull << lane) - 1ull));
          if (p < (uint32)SDCAP) sd_list[p] = ((u64)(~u) << 32) | (uint32)v;
        }
      }
    }
  }
  __syncthreads();
  const uint32 ng = n_gt < 2048u ? n_gt : 2048u;
  for (uint32 i = tid; i < ng; i += 1024){
    const int v = gt_list[i];
    const int o = nchunk * NCAND + (int)i;
    topidx[o] = v; invc_f[o] = invn_f[v]; invc_l[o] = invn_l[v];
  }
  const int n = (int)(n_sd < (uint32)SDCAP ? n_sd : (uint32)SDCAP);
  uint32 r = NCAND - cgt; if ((int)r > n) r = (uint32)n;
  u64 pref = sd_list[0] & 0xFF00000000000000ull;
  uint32 rem = r;
  const int bytes6[6] = {6,5,4,2,1,0};
  for (int bi = 0; bi < 6; ++bi){
    const int by = bytes6[bi];
    if (tid < 256) rh[tid] = 0;
    __syncthreads();
    const u64 pmask = (~0ull) << ((by+1)*8);
    for (int i = tid; i < n; i += 1024){
      u64 x = sd_list[i];
      if ((x & pmask) == pref) atomicAdd(&rh[(uint32)(x >> (by*8)) & 255u], 1u);
    }
    __syncthreads();
    if (tid < 64){
      const uint32 b0 = rh[lane*4], b1 = rh[lane*4+1], b2 = rh[lane*4+2], b3 = rh[lane*4+3];
      uint32 ps = b0 + b1 + b2 + b3;
      #pragma unroll
      for (int off = 1; off < 64; off <<= 1){
        uint32 t = __shfl_up(ps, off, 64);
        if (lane >= off) ps += t;
      }
      const u64 mm = __ballot(ps >= rem);
      const int gl = (int)__builtin_ctzll(mm);
      const uint32 before = (gl > 0) ? __shfl(ps, gl-1, 64) : 0u;
      if (lane == gl){
        uint32 cum = before; uint32 bsel = (uint32)gl * 4;
        if (cum + b0 < rem){ cum += b0; bsel++;
          if (cum + b1 < rem){ cum += b1; bsel++;
            if (cum + b2 < rem){ cum += b2; bsel++; } } }
        s_sel = bsel; s_cum = cum;
      }
    }
    __syncthreads();
    pref |= ((u64)s_sel) << (by*8);
    rem -= s_cum;
    __syncthreads();
  }
  for (int i = tid; i < n; i += 1024){
    u64 x = sd_list[i];
    if (x <= pref){
      uint32 p = atomicAdd(&s_pos, 1u);
      const int v = (int)(uint32)x;
      const int o = nchunk * NCAND + (int)(cgt + p);
      topidx[o] = v; invc_f[o] = invn_f[v]; invc_l[o] = invn_l[v];
    }
  }
}

// ------- fused GEMM: fp8 main + aux bf16, 128x64 tiles (2048 blocks, 8/CU) -----
// 4 waves, each wave owns 32 rows x all 64 cols (acc[2][4]). 32 tiles/chunk ->
// 32 partials/token (same pm/pa layout as before). XCD swizzle keeps a chunk's
// 32 tiles on one XCD (A-tile 128KB L2-resident; B gathered from L3).
__global__ void __launch_bounds__(256)
gemm_fused(const u8* __restrict__ h8, const u8* __restrict__ emb8,
           const u16* __restrict__ hlow16, const u16* __restrict__ elow16,
           const int* __restrict__ topidx,
           const float* __restrict__ invh_f, const float* __restrict__ invc_f,
           const float* __restrict__ invh_l, const float* __restrict__ invc_l,
           const int* __restrict__ tgts, const float* __restrict__ lsc,
           float* __restrict__ pm, float* __restrict__ pa)
{
  constexpr int NSTEP = 16;   // 1024 / 64
  const int id = blockIdx.x;
  const int s_ = id >> 3;
  const int ntile = s_ & 31;
  const int nchunk = ((s_ >> 5) << 3) | (id & 7);
  const int tid = threadIdx.x, lane = tid & 63, wid = tid >> 6;
  const int wm = wid;                    // wave row-group (32 rows each)
  const int fq = lane >> 4, fr = lane & 15;

  __shared__ u8 As[CCHUNK * 64];   // 8 KB fp8 (reused as bf16x32 for aux)
  __shared__ u8 Bs[64 * 64];       // 4 KB
  __shared__ float s_invh[CCHUNK], s_invhl[CCHUNK];
  __shared__ float s_invc[64], s_invcl[64];
  __shared__ int   s_tgt[CCHUNK], s_idx[64];

  if (tid < CCHUNK){
    s_invh[tid]  = invh_f[nchunk * CCHUNK + tid];
    s_invhl[tid] = invh_l[nchunk * CCHUNK + tid];
    s_tgt[tid]   = tgts[nchunk * CCHUNK + tid];
  }
  if (tid < 64){
    int o = nchunk * NCAND + ntile * 64 + tid;
    s_idx[tid]  = topidx[o];
    s_invc[tid] = invc_f[o];
    s_invcl[tid] = invc_l[o];
  }

  // staging geometry (64B rows): 16 rows per call; A: 2 calls/wave, B: 1
  const int rl = lane >> 2;
  const int cbyte = ((lane & 3) ^ (rl & 3)) * 16;   // pre-swizzled source slot
  const char* aptr[2];
  const char* alptr[2];
  const char* bptr;
  const char* blptr;
  #pragma unroll
  for (int s = 0; s < 2; ++s){
    int row = wid * 32 + s * 16 + rl;
    aptr[s]  = (const char*)h8 + ((size_t)(nchunk * CCHUNK + row)) * D_DIM + cbyte;
    alptr[s] = (const char*)hlow16 + ((size_t)(nchunk * CCHUNK + row)) * (LOWR*2) + cbyte;
  }
  {
    int brow = wid * 16 + rl;
    int cidx = topidx[nchunk * NCAND + ntile * 64 + brow];
    bptr  = (const char*)emb8 + (size_t)cidx * D_DIM + cbyte;
    blptr = (const char*)elow16 + (size_t)cidx * (LOWR*2) + cbyte;
  }

  f32x4 acc[2][4];
  #pragma unroll
  for (int m=0;m<2;++m)
    #pragma unroll
    for (int q=0;q<4;++q)
      acc[m][q] = (f32x4){0.f,0.f,0.f,0.f};

  for (int st = 0; st < NSTEP; ++st){
    const int koff = st * 64;
    gload_lds16(aptr[0] + koff, (void*)&As[(wid*32 + 0 ) * 64]);
    gload_lds16(aptr[1] + koff, (void*)&As[(wid*32 + 16) * 64]);
    gload_lds16(bptr + koff,    (void*)&Bs[(wid*16) * 64]);
    __syncthreads();
    #pragma unroll
    for (int kk = 0; kk < 2; ++kk){
      long af[2], bf[4];
      #pragma unroll
      for (int m=0;m<2;++m)
        af[m] = *(const long*)&As[a8(wm*32 + m*16 + fr, kk*4 + fq)];
      #pragma unroll
      for (int q=0;q<4;++q)
        bf[q] = *(const long*)&Bs[a8(q*16 + fr, kk*4 + fq)];
      #pragma unroll
      for (int m=0;m<2;++m)
        #pragma unroll
        for (int q=0;q<4;++q)
          acc[m][q] = __builtin_amdgcn_mfma_f32_16x16x32_fp8_fp8(af[m], bf[q], acc[m][q], 0, 0, 0);
    }
    __syncthreads();
  }

  // issue aux staging now (bf16 low-32 tables); latency hidden by main epilogue
  gload_lds16(alptr[0], (void*)&As[(wid*32 + 0 ) * 64]);
  gload_lds16(alptr[1], (void*)&As[(wid*32 + 16) * 64]);
  gload_lds16(blptr,    (void*)&Bs[(wid*16) * 64]);

  const float scale = sigscale(lsc);
  const float scm = scale * (1.0f / ESCALE);   // undo emb pre-scale (main only)
  const float NEG = -__builtin_huge_valf();

  // main epilogue -> pm (per-row partial over this tile's 64 cols)
  #pragma unroll
  for (int m=0;m<2;++m){
    #pragma unroll
    for (int j=0;j<4;++j){
      const int c = wm*32 + m*16 + fq*4 + j;
      const float ihs = s_invh[c] * scm;
      const int tg = s_tgt[c];
      float vals[4];
      #pragma unroll
      for (int q=0;q<4;++q){
        const int kl = q*16 + fr;
        float lg = acc[m][q][j] * ihs * s_invc[kl];
        vals[q] = (s_idx[kl] == tg) ? NEG : lg;
      }
      float lmax = fmaxf(fmaxf(vals[0], vals[1]), fmaxf(vals[2], vals[3]));
      #pragma unroll
      for (int ms=1; ms<16; ms<<=1) lmax = fmaxf(lmax, __shfl_xor(lmax, ms, 64));
      float se = 0.f;
      #pragma unroll
      for (int q=0;q<4;++q) se += __expf(vals[q] - lmax);
      #pragma unroll
      for (int ms=1; ms<16; ms<<=1) se += __shfl_xor(se, ms, 64);
      if (fr == 0){
        size_t pos = ((size_t)(nchunk*32 + ntile) * CCHUNK + c) * 2;
        pm[pos]   = lmax;
        pm[pos+1] = se;
      }
    }
  }

  __syncthreads();   // aux staging drained

  // aux compute (bf16): one MFMA per fragment pair; 64B rows, 16B slot = fq
  f32x4 acc2[2][4];
  {
    short8 afa[2], bfa[4];
    #pragma unroll
    for (int m=0;m<2;++m){
      const int r = wm*32 + m*16 + fr;
      afa[m] = *(const short8*)&As[r*64 + ((fq ^ (r & 3)) << 4)];
    }
    #pragma unroll
    for (int q=0;q<4;++q){
      const int r = q*16 + fr;
      bfa[q] = *(const short8*)&Bs[r*64 + ((fq ^ (r & 3)) << 4)];
    }
    #pragma unroll
    for (int m=0;m<2;++m)
      #pragma unroll
      for (int q=0;q<4;++q)
        acc2[m][q] = __builtin_amdgcn_mfma_f32_16x16x32_bf16(
            afa[m], bfa[q], (f32x4){0.f,0.f,0.f,0.f}, 0, 0, 0);
  }

  // aux epilogue -> pa
  #pragma unroll
  for (int m=0;m<2;++m){
    #pragma unroll
    for (int j=0;j<4;++j){
      const int c = wm*32 + m*16 + fq*4 + j;
      const float ihs = s_invhl[c] * scale;
      const int tg = s_tgt[c];
      float vals[4];
      #pragma unroll
      for (int q=0;q<4;++q){
        const int kl = q*16 + fr;
        float lg = acc2[m][q][j] * ihs * s_invcl[kl];
        vals[q] = (s_idx[kl] == tg) ? NEG : lg;
      }
      float lmax = fmaxf(fmaxf(vals[0], vals[1]), fmaxf(vals[2], vals[3]));
      #pragma unroll
      for (int ms=1; ms<16; ms<<=1) lmax = fmaxf(lmax, __shfl_xor(lmax, ms, 64));
      float se = 0.f;
      #pragma unroll
      for (int q=0;q<4;++q) se += __expf(vals[q] - lmax);
      #pragma unroll
      for (int ms=1; ms<16; ms<<=1) se += __shfl_xor(se, ms, 64);
      if (fr == 0){
        size_t pos = ((size_t)(nchunk*32 + ntile) * CCHUNK + c) * 2;
        pa[pos]   = lmax;
        pa[pos+1] = se;
      }
    }
  }
}

// ---- merge partials + fp32 target term -> scalar loss -------------------------
__global__ void __launch_bounds__(256)
merge_loss(const float* __restrict__ h, const float* __restrict__ emb,
           const int* __restrict__ tgts,
           const float* __restrict__ invh_f, const float* __restrict__ invh_l,
           const float* __restrict__ invn_f, const float* __restrict__ invn_l,
           const float* __restrict__ pm, const float* __restrict__ pa,
           const float* __restrict__ lsc, float* __restrict__ out)
{
  const int nchunk = blockIdx.x >> 2, quarter = blockIdx.x & 3;
  const int tid = threadIdx.x, lane = tid & 63, wid = tid >> 6;
  const float scale = sigscale(lsc);
  const float NEG = -__builtin_huge_valf();
  float wacc = 0.f;
  for (int i = 0; i < 8; ++i){
    const int loc = quarter*32 + wid*8 + i;
    const int tok = nchunk * CCHUNK + loc;
    const int t = tgts[tok];
    float hf[16], ef[16];
    load_row16(h + (size_t)tok * D_DIM, lane, hf);
    load_row16(emb + (size_t)t * D_DIM, lane, ef);
    float part = 0.f;
    #pragma unroll
    for (int k=0;k<16;++k) part += hf[k]*ef[k];
    float dfull = wred_sum(part);
    float dlow  = wred_sum(lane < 2 ? part : 0.f);
    float tful = dfull * invh_f[tok] * invn_f[t] * scale;
    float tlow = dlow  * invh_l[tok] * invn_l[t] * scale;

    float mi = NEG, si = 0.f, mia = NEG, sia = 0.f;
    if (lane < 32){
      size_t q = ((size_t)(nchunk*32 + lane) * CCHUNK + loc) * 2;
      mi  = pm[q]; si  = pm[q+1];
      mia = pa[q]; sia = pa[q+1];
    }
    float M  = wred_max(mi);
    float S  = wred_sum(lane < 32 ? si * __expf(mi - M) : 0.f);
    float M2 = fmaxf(M, tful);
    float lmain = __logf(S * __expf(M - M2) + __expf(tful - M2)) + M2 - tful;
    float Ma  = wred_max(mia);
    float Sa  = wred_sum(lane < 32 ? sia * __expf(mia - Ma) : 0.f);
    float M2a = fmaxf(Ma, tlow);
    float laux = __logf(Sa * __expf(Ma - M2a) + __expf(tlow - M2a)) + M2a - tlow;
    wacc += lmain + 0.2f * laux;
  }
  __shared__ float ws4[4];
  if (lane == 0) ws4[wid] = wacc;
  __syncthreads();
  if (tid == 0) atomicAdd(out, (ws4[0]+ws4[1]+ws4[2]+ws4[3]) * (1.f / (float)T_TOK));
}

// ---------------- host ---------------------------------------------------------
extern "C" void kernel_launch(void* const* d_in, const int* in_sizes, int n_in,
                              void* d_out, int out_size, void* d_ws, size_t ws_size,
                              hipStream_t stream)
{
  (void)in_sizes; (void)n_in; (void)out_size; (void)ws_size;
  const float* h   = (const float*)d_in[0];
  const float* emb = (const float*)d_in[1];
  const float* lsc = (const float*)d_in[2];
  const int*   tgt = (const int*)d_in[3];
  float* out = (float*)d_out;

  uint8_t* p = (uint8_t*)d_ws;
  auto carve = [&](size_t n)->uint8_t*{
    uint8_t* r = p; p += (n + 255) & ~(size_t)255; return r;
  };
  u8*    emb8   = (u8*)   carve((size_t)V_SIZE * D_DIM);
  u16*   elow16 = (u16*)  carve((size_t)V_SIZE * LOWR * 2);
  float* invn_f = (float*)carve((size_t)V_SIZE * 4);
  float* invn_l = (float*)carve((size_t)V_SIZE * 4);
  float* wlow   = (float*)carve((size_t)V_SIZE * LOWR * 4);
  u8*    h8     = (u8*)   carve((size_t)T_TOK * D_DIM);
  u16*   hlow16 = (u16*)  carve((size_t)T_TOK * LOWR * 2);
  float* invh_f = (float*)carve((size_t)T_TOK * 4);
  float* invh_l = (float*)carve((size_t)T_TOK * 4);
  float* hpart  = (float*)carve((size_t)NCHUNK * 8 * LOWR * 4);
  float* scan   = (float*)carve((size_t)NCHUNK * V_PAD * 4);
  int*   topidx = (int*)  carve((size_t)NCHUNK * NCAND * 4);
  float* invc_f = (float*)carve((size_t)NCHUNK * NCAND * 4);
  float* invc_l = (float*)carve((size_t)NCHUNK * NCAND * 4);
  float* pm     = (float*)carve((size_t)NCHUNK * 32 * CCHUNK * 2 * 4);
  float* pa     = (float*)carve((size_t)NCHUNK * 32 * CCHUNK * 2 * 4);

  prep_kernel<<<dim3(NVB + NCHUNK*8), dim3(256), 0, stream>>>(
      emb, emb8, elow16, invn_f, invn_l, wlow, h, h8, hlow16, invh_f, invh_l, hpart, out);
  scan_kernel<<<dim3(V_PAD / 256), dim3(256), 0, stream>>>(wlow, invn_l, hpart, scan);
  topk_all<<<dim3(NCHUNK), dim3(1024), 0, stream>>>(
      scan, invn_f, invn_l, topidx, invc_f, invc_l);
  gemm_fused<<<dim3(32 * NCHUNK), dim3(256), 0, stream>>>(
      h8, emb8, hlow16, elow16, topidx, invh_f, invc_f, invh_l, invc_l, tgt, lsc, pm, pa);
  merge_loss<<<dim3(NCHUNK * 4), dim3(256), 0, stream>>>(
      h, emb, tgt, invh_f, invh_l, invn_f, invn_l, pm, pa, lsc, out);
}

// Round 10
// 187.615 us; speedup vs baseline: 1.0328x; 1.0269x over previous
//
#include <hip/hip_runtime.h>
#include <cstdint>
#include <cstddef>

#define V_SIZE 50257
#define V_PAD  50432
#define NV4    (V_PAD/4)
#define NVB    ((V_SIZE + 3) / 4)
#define D_DIM  1024
#define T_TOK  8192
#define NCHUNK 64
#define CCHUNK 128
#define NCAND  2048
#define LOWR   32
#define SDCAP  4096
#define ESCALE 32.0f   // emb pre-scale before fp8 (power of 2; folded out in epilogue)

typedef unsigned int  uint32;
typedef unsigned short u16;
typedef unsigned char u8;
typedef unsigned long long u64;
typedef __attribute__((ext_vector_type(8))) short short8;
typedef __attribute__((ext_vector_type(4))) float f32x4;

__device__ __forceinline__ u16 f2bf(float f){
  uint32 u = __float_as_uint(f);
  return (u16)((u + 0x7FFFu + ((u >> 16) & 1u)) >> 16);
}
__device__ __forceinline__ uint32 key_of(float f){
  uint32 b = __float_as_uint(f);
  return b ^ ((uint32)((int)b >> 31) | 0x80000000u);
}
// monotone fixed-point bin for scan values (|x| < ~0.15; uniform 1/4096 bins)
__device__ __forceinline__ int fxbin(float x){
  float c = fmaxf(fminf(x, 0.49f), -0.49f);
  int b = (int)(c * 4096.f) + 1024;
  return b < 0 ? 0 : (b > 2047 ? 2047 : b);
}
__device__ __forceinline__ float sigscale(const float* lsc){
  return 100.f / (1.f + __expf(-lsc[0])) + 1.f;
}
__device__ __forceinline__ float wred_sum(float v){
  #pragma unroll
  for (int m = 32; m >= 1; m >>= 1) v += __shfl_xor(v, m, 64);
  return v;
}
__device__ __forceinline__ float wred_max(float v){
  #pragma unroll
  for (int m = 32; m >= 1; m >>= 1) v = fmaxf(v, __shfl_xor(v, m, 64));
  return v;
}
__device__ __forceinline__ void gload_lds16(const void* g, void* l){
  __builtin_amdgcn_global_load_lds(
      (const __attribute__((address_space(1))) uint32*)g,
      (__attribute__((address_space(3))) uint32*)l, 16, 0, 0);
}
__device__ __forceinline__ void load_row16(const float* base, int lane, float* f){
  const float4* s4 = (const float4*)(base + lane * 16);
  float4 t0 = s4[0], t1 = s4[1], t2 = s4[2], t3 = s4[3];
  f[0]=t0.x; f[1]=t0.y; f[2]=t0.z;  f[3]=t0.w;
  f[4]=t1.x; f[5]=t1.y; f[6]=t1.z;  f[7]=t1.w;
  f[8]=t2.x; f[9]=t2.y; f[10]=t2.z; f[11]=t2.w;
  f[12]=t3.x; f[13]=t3.y; f[14]=t3.z; f[15]=t3.w;
}
__device__ __forceinline__ void store_bf16x16(u16* dst_base, int lane, const float* f){
  uint32 pk[8];
  #pragma unroll
  for (int i=0;i<8;++i) pk[i] = (uint32)f2bf(f[2*i]) | ((uint32)f2bf(f[2*i+1]) << 16);
  uint4* d = (uint4*)(dst_base + lane * 16);
  d[0] = make_uint4(pk[0],pk[1],pk[2],pk[3]);
  d[1] = make_uint4(pk[4],pk[5],pk[6],pk[7]);
}
__device__ __forceinline__ void store_fp8x16(u8* dst_base, int lane, const float* f, float sc){
  uint32 pk[4];
  #pragma unroll
  for (int i=0;i<4;++i){
    int w = __builtin_amdgcn_cvt_pk_fp8_f32(f[4*i]*sc,   f[4*i+1]*sc, 0, false);
    w     = __builtin_amdgcn_cvt_pk_fp8_f32(f[4*i+2]*sc, f[4*i+3]*sc, w, true);
    pk[i] = (uint32)w;
  }
  *(uint4*)(dst_base + lane * 16) = make_uint4(pk[0],pk[1],pk[2],pk[3]);
}
// fp8 fragment read address within a 64B-row LDS tile (both-sides 16B XOR swizzle)
__device__ __forceinline__ int a8(int r, int slot8){
  return r*64 + ((((slot8>>1) ^ (r&3))) << 4) + ((slot8&1) << 3);
}

// ------- fused prep: vocab (blocks [0,NVB)) + tokens (blocks [NVB,NVB+512)) ----
__global__ void __launch_bounds__(256)
prep_kernel(const float* __restrict__ emb, u8* __restrict__ emb8,
            u16* __restrict__ elow16,
            float* __restrict__ invn_f, float* __restrict__ invn_l,
            float* __restrict__ wlow,
            const float* __restrict__ h, u8* __restrict__ h8,
            u16* __restrict__ hlow16,
            float* __restrict__ invh_f, float* __restrict__ invh_l,
            float* __restrict__ hpart, uint32* __restrict__ ghist,
            float* __restrict__ out)
{
  const int bid = blockIdx.x;
  const int tid = threadIdx.x, lane = tid & 63, wid = tid >> 6;
  if (bid < NVB){
    if (bid == 0 && tid == 0) out[0] = 0.f;   // zero loss accumulator
    // first 512 blocks also zero ghist (64 chunks x 2048 bins), 1KB each
    if (bid < 512 && tid < 64)
      ((uint4*)ghist)[bid * 64 + tid] = make_uint4(0,0,0,0);
    const int v = bid * 4 + wid;
    if (v >= V_SIZE) return;
    float f[16];
    load_row16(emb + (size_t)v * D_DIM, lane, f);
    float ss = 0.f;
    #pragma unroll
    for (int k=0;k<16;++k) ss += f[k]*f[k];
    float fullss = wred_sum(ss);
    float lowss  = wred_sum(lane < 2 ? ss : 0.f);   // lanes 0,1 own elems 0..31
    store_fp8x16(emb8 + (size_t)v * D_DIM, lane, f, ESCALE);
    if (lane < 2){
      store_bf16x16(elow16 + (size_t)v * LOWR, lane, f);
      float4* wp = (float4*)(wlow + (size_t)v * LOWR + lane * 16);
      wp[0] = make_float4(f[0], f[1], f[2],  f[3]);
      wp[1] = make_float4(f[4], f[5], f[6],  f[7]);
      wp[2] = make_float4(f[8], f[9], f[10], f[11]);
      wp[3] = make_float4(f[12],f[13],f[14], f[15]);
    }
    if (lane == 0){
      invn_f[v] = 1.f / fmaxf(sqrtf(fullss), 1e-12f);
      invn_l[v] = 1.f / fmaxf(sqrtf(lowss),  1e-12f);
    }
    return;
  }
  // token path
  const int bid2 = bid - NVB;
  const int nchunk = bid2 >> 3, sub = bid2 & 7;
  __shared__ float hm[LOWR];
  if (tid < LOWR) hm[tid] = 0.f;
  __syncthreads();
  for (int i = 0; i < 4; ++i){
    const int loc = sub*16 + wid*4 + i;
    const int tok = nchunk * CCHUNK + loc;
    float f[16];
    load_row16(h + (size_t)tok * D_DIM, lane, f);
    float ss = 0.f;
    #pragma unroll
    for (int k=0;k<16;++k) ss += f[k]*f[k];
    float fullss = wred_sum(ss);
    float lowss  = wred_sum(lane < 2 ? ss : 0.f);
    float invf = 1.f / fmaxf(sqrtf(fullss), 1e-12f);
    float invl = 1.f / fmaxf(sqrtf(lowss),  1e-12f);
    store_fp8x16(h8 + (size_t)tok * D_DIM, lane, f, 1.0f);
    if (lane < 2) store_bf16x16(hlow16 + (size_t)tok * LOWR, lane, f);
    if (lane == 0){ invh_f[tok] = invf; invh_l[tok] = invl; }
    if (lane < 2){
      #pragma unroll
      for (int k=0;k<16;++k) atomicAdd(&hm[lane*16 + k], f[k] * invl * (1.f/128.f));
    }
  }
  __syncthreads();
  if (tid < LOWR) hpart[(size_t)(nchunk*8 + sub) * LOWR + tid] = hm[tid];
}

// -------- scan: scan[n][v] = h_mean[n] . (wlow[v] * invn_l[v]) (compact read) --
__global__ void __launch_bounds__(256)
scan_kernel(const float* __restrict__ wlow, const float* __restrict__ invn_l,
            const float* __restrict__ hpart, float* __restrict__ scan)
{
  __shared__ float hm[NCHUNK * LOWR];
  for (int i = threadIdx.x; i < NCHUNK * LOWR; i += 256){
    const int nn = i >> 5, l = i & 31;
    float s = 0.f;
    #pragma unroll
    for (int p = 0; p < 8; ++p) s += hpart[(size_t)(nn*8 + p) * LOWR + l];
    hm[i] = s;
  }
  __syncthreads();
  const int v = blockIdx.x * 256 + threadIdx.x;
  if (v >= V_SIZE){
    if (v < V_PAD)
      for (int nn = 0; nn < NCHUNK; ++nn) scan[(size_t)nn * V_PAD + v] = -3.4e38f;
    return;
  }
  float w[LOWR];
  const float4* s4 = (const float4*)(wlow + (size_t)v * LOWR);
  #pragma unroll
  for (int i=0;i<8;++i){
    float4 t = s4[i];
    w[4*i]=t.x; w[4*i+1]=t.y; w[4*i+2]=t.z; w[4*i+3]=t.w;
  }
  const float inv = invn_l[v];
  #pragma unroll
  for (int i=0;i<LOWR;++i) w[i] *= inv;
  for (int nn = 0; nn < NCHUNK; ++nn){
    float d = 0.f;
    #pragma unroll
    for (int l=0;l<LOWR;++l) d += w[l] * hm[nn*LOWR + l];
    scan[(size_t)nn * V_PAD + v] = d;
  }
}

// ---- topk stage A (64x8 blocks): fixed-point 2048-bin hist -> global merge ----
__global__ void __launch_bounds__(256)
topk_hist(const float* __restrict__ scan, uint32* __restrict__ ghist)
{
  const int nchunk = blockIdx.x, sub = blockIdx.y, tid = threadIdx.x;
  __shared__ uint32 hh[4][2048];   // 32 KB, 4-way privatized
  for (int i = tid; i < 4*2048; i += 256) (&hh[0][0])[i] = 0;
  __syncthreads();
  const int cp = (tid >> 6) & 3;
  const float4* row = (const float4*)(scan + (size_t)nchunk * V_PAD) + sub * (NV4/8);
  for (int i = tid; i < NV4/8; i += 256){
    float4 x = row[i];
    atomicAdd(&hh[cp][fxbin(x.x)], 1u);
    atomicAdd(&hh[cp][fxbin(x.y)], 1u);
    atomicAdd(&hh[cp][fxbin(x.z)], 1u);
    atomicAdd(&hh[cp][fxbin(x.w)], 1u);
  }
  __syncthreads();
  uint32* gh = ghist + nchunk * 2048;
  for (int i = tid; i < 2048; i += 256){
    uint32 s = hh[0][i] + hh[1][i] + hh[2][i] + hh[3][i];
    if (s) atomicAdd(&gh[i], s);
  }
}

// ---- topk stage B (64 blocks): threshold + classify + exact refine ------------
__global__ void __launch_bounds__(1024)
topk_select(const float* __restrict__ scan, const uint32* __restrict__ ghist,
            const float* __restrict__ invn_f, const float* __restrict__ invn_l,
            int* __restrict__ topidx, float* __restrict__ invc_f, float* __restrict__ invc_l)
{
  const int nchunk = blockIdx.x, tid = threadIdx.x, lane = tid & 63;
  __shared__ uint32 h[2048];          //  8 KB
  __shared__ int gt_list[2048];       //  8 KB
  __shared__ u64 sd_list[SDCAP];      // 32 KB
  __shared__ uint32 rh[256];          //  1 KB
  __shared__ uint32 n_gt, n_sd, s_tb, s_cgt, s_sel, s_cum, s_pos;
  if (tid == 0){ n_gt = 0; n_sd = 0; s_pos = 0; }
  for (int i = tid; i < 2048; i += 1024) h[i] = ghist[nchunk * 2048 + i];
  __syncthreads();
  // threshold: wave 0, coarse 64 groups x 32 bins (descending suffix scans)
  if (tid < 64){
    uint32 c = 0;
    #pragma unroll 8
    for (int k = 0; k < 32; ++k) c += h[lane*32 + k];
    uint32 s = c;
    #pragma unroll
    for (int off = 1; off < 64; off <<= 1){
      uint32 t = __shfl_down(s, off, 64);
      if (lane + off < 64) s += t;
    }
    u64 m1 = __ballot(s >= NCAND);
    const int g = 63 - __builtin_clzll(m1);
    const uint32 cum = (g < 63) ? __shfl(s, g + 1, 64) : 0u;
    uint32 s2 = (lane < 32) ? h[g*32 + lane] : 0u;
    #pragma unroll
    for (int off = 1; off < 32; off <<= 1){
      uint32 t = __shfl_down(s2, off, 64);
      if (lane + off < 32) s2 += t;
    }
    u64 m2 = __ballot((lane < 32) && (cum + s2 >= NCAND));
    const int j = 63 - __builtin_clzll(m2);
    const uint32 cgt = cum + ((j < 31) ? __shfl(s2, j + 1, 64) : 0u);
    if (lane == 0){ s_tb = (uint32)(g*32 + j); s_cgt = cgt; }
  }
  __syncthreads();
  const int tb = (int)s_tb;
  const uint32 cgt = s_cgt;
  // classify pass: wave-aggregated appends to LDS lists
  const float4* row = (const float4*)(scan + (size_t)nchunk * V_PAD);
  for (int i = tid; i < NV4; i += 1024){
    float4 x = row[i];
    const int vbase = i * 4;
    float vals[4] = {x.x, x.y, x.z, x.w};
    #pragma unroll
    for (int c = 0; c < 4; ++c){
      const int b = fxbin(vals[c]);
      const int v = vbase + c;
      const bool ok = (v < V_SIZE) && (b >= tb);
      const bool is_gt = ok && (b > tb);
      const bool is_sd = ok && (b == tb);
      const u64 mg = __ballot(is_gt);
      if (mg){
        const int ldr = (int)__builtin_ctzll(mg);
        uint32 base = 0;
        if (lane == ldr) base = atomicAdd(&n_gt, (uint32)__popcll(mg));
        base = __shfl(base, ldr, 64);
        if (is_gt){
          uint32 p = base + (uint32)__popcll(mg & ((1ull << lane) - 1ull));
          if (p < 2048u) gt_list[p] = v;
        }
      }
      const u64 ms = __ballot(is_sd);
      if (ms){
        const int ldr = (int)__builtin_ctzll(ms);
        uint32 base = 0;
        if (lane == ldr) base = atomicAdd(&n_sd, (uint32)__popcll(ms));
        base = __shfl(base, ldr, 64);
        if (is_sd){
          uint32 p = base + (uint32)__popcll(ms & ((1ull << lane) - 1ull));
          if (p < (uint32)SDCAP)
            sd_list[p] = ((u64)(~key_of(vals[c])) << 32) | (uint32)v;
        }
      }
    }
  }
  __syncthreads();
  // write strictly-greater candidates
  const uint32 ng = n_gt < 2048u ? n_gt : 2048u;
  for (uint32 i = tid; i < ng; i += 1024){
    const int v = gt_list[i];
    const int o = nchunk * NCAND + (int)i;
    topidx[o] = v; invc_f[o] = invn_f[v]; invc_l[o] = invn_l[v];
  }
  // refine: r-th smallest u64 (exact float keys); v < 2^16 -> bytes 3,2 are 0
  const int n = (int)(n_sd < (uint32)SDCAP ? n_sd : (uint32)SDCAP);
  uint32 r = NCAND - cgt; if ((int)r > n) r = (uint32)n;
  u64 pref = 0;
  uint32 rem = r;
  const int bytes6[6] = {7,6,5,4,1,0};
  for (int bi = 0; bi < 6; ++bi){
    const int by = bytes6[bi];
    if (tid < 256) rh[tid] = 0;
    __syncthreads();
    const u64 pmask = (by == 7) ? 0ull : ((~0ull) << ((by+1)*8));
    for (int i = tid; i < n; i += 1024){
      u64 x = sd_list[i];
      if ((x & pmask) == pref) atomicAdd(&rh[(uint32)(x >> (by*8)) & 255u], 1u);
    }
    __syncthreads();
    if (tid < 64){
      const uint32 b0 = rh[lane*4], b1 = rh[lane*4+1], b2 = rh[lane*4+2], b3 = rh[lane*4+3];
      uint32 ps = b0 + b1 + b2 + b3;
      #pragma unroll
      for (int off = 1; off < 64; off <<= 1){
        uint32 t = __shfl_up(ps, off, 64);
        if (lane >= off) ps += t;
      }
      const u64 mm = __ballot(ps >= rem);
      const int gl = (int)__builtin_ctzll(mm);
      const uint32 before = (gl > 0) ? __shfl(ps, gl-1, 64) : 0u;
      if (lane == gl){
        uint32 cum = before; uint32 bsel = (uint32)gl * 4;
        if (cum + b0 < rem){ cum += b0; bsel++;
          if (cum + b1 < rem){ cum += b1; bsel++;
            if (cum + b2 < rem){ cum += b2; bsel++; } } }
        s_sel = bsel; s_cum = cum;
      }
    }
    __syncthreads();
    pref |= ((u64)s_sel) << (by*8);
    rem -= s_cum;
    __syncthreads();
  }
  for (int i = tid; i < n; i += 1024){
    u64 x = sd_list[i];
    if (x <= pref){
      uint32 p = atomicAdd(&s_pos, 1u);
      const int v = (int)(uint32)x;
      const int o = nchunk * NCAND + (int)(cgt + p);
      topidx[o] = v; invc_f[o] = invn_f[v]; invc_l[o] = invn_l[v];
    }
  }
}

// ------- fused GEMM: fp8 main + aux bf16, 128x64 tiles (2048 blocks, 8/CU) -----
__global__ void __launch_bounds__(256)
gemm_fused(const u8* __restrict__ h8, const u8* __restrict__ emb8,
           const u16* __restrict__ hlow16, const u16* __restrict__ elow16,
           const int* __restrict__ topidx,
           const float* __restrict__ invh_f, const float* __restrict__ invc_f,
           const float* __restrict__ invh_l, const float* __restrict__ invc_l,
           const int* __restrict__ tgts, const float* __restrict__ lsc,
           float* __restrict__ pm, float* __restrict__ pa)
{
  constexpr int NSTEP = 16;   // 1024 / 64
  const int id = blockIdx.x;
  const int s_ = id >> 3;
  const int ntile = s_ & 31;
  const int nchunk = ((s_ >> 5) << 3) | (id & 7);
  const int tid = threadIdx.x, lane = tid & 63, wid = tid >> 6;
  const int wm = wid;                    // wave row-group (32 rows each)
  const int fq = lane >> 4, fr = lane & 15;

  __shared__ u8 As[CCHUNK * 64];   // 8 KB fp8 (reused as bf16x32 for aux)
  __shared__ u8 Bs[64 * 64];       // 4 KB
  __shared__ float s_invh[CCHUNK], s_invhl[CCHUNK];
  __shared__ float s_invc[64], s_invcl[64];
  __shared__ int   s_tgt[CCHUNK], s_idx[64];

  if (tid < CCHUNK){
    s_invh[tid]  = invh_f[nchunk * CCHUNK + tid];
    s_invhl[tid] = invh_l[nchunk * CCHUNK + tid];
    s_tgt[tid]   = tgts[nchunk * CCHUNK + tid];
  }
  if (tid < 64){
    int o = nchunk * NCAND + ntile * 64 + tid;
    s_idx[tid]  = topidx[o];
    s_invc[tid] = invc_f[o];
    s_invcl[tid] = invc_l[o];
  }

  // staging geometry (64B rows): 16 rows per call; A: 2 calls/wave, B: 1
  const int rl = lane >> 2;
  const int cbyte = ((lane & 3) ^ (rl & 3)) * 16;   // pre-swizzled source slot
  const char* aptr[2];
  const char* alptr[2];
  const char* bptr;
  const char* blptr;
  #pragma unroll
  for (int s = 0; s < 2; ++s){
    int row = wid * 32 + s * 16 + rl;
    aptr[s]  = (const char*)h8 + ((size_t)(nchunk * CCHUNK + row)) * D_DIM + cbyte;
    alptr[s] = (const char*)hlow16 + ((size_t)(nchunk * CCHUNK + row)) * (LOWR*2) + cbyte;
  }
  {
    int brow = wid * 16 + rl;
    int cidx = topidx[nchunk * NCAND + ntile * 64 + brow];
    bptr  = (const char*)emb8 + (size_t)cidx * D_DIM + cbyte;
    blptr = (const char*)elow16 + (size_t)cidx * (LOWR*2) + cbyte;
  }

  f32x4 acc[2][4];
  #pragma unroll
  for (int m=0;m<2;++m)
    #pragma unroll
    for (int q=0;q<4;++q)
      acc[m][q] = (f32x4){0.f,0.f,0.f,0.f};

  for (int st = 0; st < NSTEP; ++st){
    const int koff = st * 64;
    gload_lds16(aptr[0] + koff, (void*)&As[(wid*32 + 0 ) * 64]);
    gload_lds16(aptr[1] + koff, (void*)&As[(wid*32 + 16) * 64]);
    gload_lds16(bptr + koff,    (void*)&Bs[(wid*16) * 64]);
    __syncthreads();
    #pragma unroll
    for (int kk = 0; kk < 2; ++kk){
      long af[2], bf[4];
      #pragma unroll
      for (int m=0;m<2;++m)
        af[m] = *(const long*)&As[a8(wm*32 + m*16 + fr, kk*4 + fq)];
      #pragma unroll
      for (int q=0;q<4;++q)
        bf[q] = *(const long*)&Bs[a8(q*16 + fr, kk*4 + fq)];
      #pragma unroll
      for (int m=0;m<2;++m)
        #pragma unroll
        for (int q=0;q<4;++q)
          acc[m][q] = __builtin_amdgcn_mfma_f32_16x16x32_fp8_fp8(af[m], bf[q], acc[m][q], 0, 0, 0);
    }
    __syncthreads();
  }

  // issue aux staging now (bf16 low-32 tables); latency hidden by main epilogue
  gload_lds16(alptr[0], (void*)&As[(wid*32 + 0 ) * 64]);
  gload_lds16(alptr[1], (void*)&As[(wid*32 + 16) * 64]);
  gload_lds16(blptr,    (void*)&Bs[(wid*16) * 64]);

  const float scale = sigscale(lsc);
  const float scm = scale * (1.0f / ESCALE);   // undo emb pre-scale (main only)
  const float NEG = -__builtin_huge_valf();

  // main epilogue -> pm (per-row partial over this tile's 64 cols)
  #pragma unroll
  for (int m=0;m<2;++m){
    #pragma unroll
    for (int j=0;j<4;++j){
      const int c = wm*32 + m*16 + fq*4 + j;
      const float ihs = s_invh[c] * scm;
      const int tg = s_tgt[c];
      float vals[4];
      #pragma unroll
      for (int q=0;q<4;++q){
        const int kl = q*16 + fr;
        float lg = acc[m][q][j] * ihs * s_invc[kl];
        vals[q] = (s_idx[kl] == tg) ? NEG : lg;
      }
      float lmax = fmaxf(fmaxf(vals[0], vals[1]), fmaxf(vals[2], vals[3]));
      #pragma unroll
      for (int ms=1; ms<16; ms<<=1) lmax = fmaxf(lmax, __shfl_xor(lmax, ms, 64));
      float se = 0.f;
      #pragma unroll
      for (int q=0;q<4;++q) se += __expf(vals[q] - lmax);
      #pragma unroll
      for (int ms=1; ms<16; ms<<=1) se += __shfl_xor(se, ms, 64);
      if (fr == 0){
        size_t pos = ((size_t)(nchunk*32 + ntile) * CCHUNK + c) * 2;
        pm[pos]   = lmax;
        pm[pos+1] = se;
      }
    }
  }

  __syncthreads();   // aux staging drained

  // aux compute (bf16): one MFMA per fragment pair; 64B rows, 16B slot = fq
  f32x4 acc2[2][4];
  {
    short8 afa[2], bfa[4];
    #pragma unroll
    for (int m=0;m<2;++m){
      const int r = wm*32 + m*16 + fr;
      afa[m] = *(const short8*)&As[r*64 + ((fq ^ (r & 3)) << 4)];
    }
    #pragma unroll
    for (int q=0;q<4;++q){
      const int r = q*16 + fr;
      bfa[q] = *(const short8*)&Bs[r*64 + ((fq ^ (r & 3)) << 4)];
    }
    #pragma unroll
    for (int m=0;m<2;++m)
      #pragma unroll
      for (int q=0;q<4;++q)
        acc2[m][q] = __builtin_amdgcn_mfma_f32_16x16x32_bf16(
            afa[m], bfa[q], (f32x4){0.f,0.f,0.f,0.f}, 0, 0, 0);
  }

  // aux epilogue -> pa
  #pragma unroll
  for (int m=0;m<2;++m){
    #pragma unroll
    for (int j=0;j<4;++j){
      const int c = wm*32 + m*16 + fq*4 + j;
      const float ihs = s_invhl[c] * scale;
      const int tg = s_tgt[c];
      float vals[4];
      #pragma unroll
      for (int q=0;q<4;++q){
        const int kl = q*16 + fr;
        float lg = acc2[m][q][j] * ihs * s_invcl[kl];
        vals[q] = (s_idx[kl] == tg) ? NEG : lg;
      }
      float lmax = fmaxf(fmaxf(vals[0], vals[1]), fmaxf(vals[2], vals[3]));
      #pragma unroll
      for (int ms=1; ms<16; ms<<=1) lmax = fmaxf(lmax, __shfl_xor(lmax, ms, 64));
      float se = 0.f;
      #pragma unroll
      for (int q=0;q<4;++q) se += __expf(vals[q] - lmax);
      #pragma unroll
      for (int ms=1; ms<16; ms<<=1) se += __shfl_xor(se, ms, 64);
      if (fr == 0){
        size_t pos = ((size_t)(nchunk*32 + ntile) * CCHUNK + c) * 2;
        pa[pos]   = lmax;
        pa[pos+1] = se;
      }
    }
  }
}

// ---- merge partials + fp32 target term -> scalar loss -------------------------
__global__ void __launch_bounds__(256)
merge_loss(const float* __restrict__ h, const float* __restrict__ emb,
           const int* __restrict__ tgts,
           const float* __restrict__ invh_f, const float* __restrict__ invh_l,
           const float* __restrict__ invn_f, const float* __restrict__ invn_l,
           const float* __restrict__ pm, const float* __restrict__ pa,
           const float* __restrict__ lsc, float* __restrict__ out)
{
  const int nchunk = blockIdx.x >> 2, quarter = blockIdx.x & 3;
  const int tid = threadIdx.x, lane = tid & 63, wid = tid >> 6;
  const float scale = sigscale(lsc);
  const float NEG = -__builtin_huge_valf();
  float wacc = 0.f;
  for (int i = 0; i < 8; ++i){
    const int loc = quarter*32 + wid*8 + i;
    const int tok = nchunk * CCHUNK + loc;
    const int t = tgts[tok];
    float hf[16], ef[16];
    load_row16(h + (size_t)tok * D_DIM, lane, hf);
    load_row16(emb + (size_t)t * D_DIM, lane, ef);
    float part = 0.f;
    #pragma unroll
    for (int k=0;k<16;++k) part += hf[k]*ef[k];
    float dfull = wred_sum(part);
    float dlow  = wred_sum(lane < 2 ? part : 0.f);
    float tful = dfull * invh_f[tok] * invn_f[t] * scale;
    float tlow = dlow  * invh_l[tok] * invn_l[t] * scale;

    float mi = NEG, si = 0.f, mia = NEG, sia = 0.f;
    if (lane < 32){
      size_t q = ((size_t)(nchunk*32 + lane) * CCHUNK + loc) * 2;
      mi  = pm[q]; si  = pm[q+1];
      mia = pa[q]; sia = pa[q+1];
    }
    float M  = wred_max(mi);
    float S  = wred_sum(lane < 32 ? si * __expf(mi - M) : 0.f);
    float M2 = fmaxf(M, tful);
    float lmain = __logf(S * __expf(M - M2) + __expf(tful - M2)) + M2 - tful;
    float Ma  = wred_max(mia);
    float Sa  = wred_sum(lane < 32 ? sia * __expf(mia - Ma) : 0.f);
    float M2a = fmaxf(Ma, tlow);
    float laux = __logf(Sa * __expf(Ma - M2a) + __expf(tlow - M2a)) + M2a - tlow;
    wacc += lmain + 0.2f * laux;
  }
  __shared__ float ws4[4];
  if (lane == 0) ws4[wid] = wacc;
  __syncthreads();
  if (tid == 0) atomicAdd(out, (ws4[0]+ws4[1]+ws4[2]+ws4[3]) * (1.f / (float)T_TOK));
}

// ---------------- host ---------------------------------------------------------
extern "C" void kernel_launch(void* const* d_in, const int* in_sizes, int n_in,
                              void* d_out, int out_size, void* d_ws, size_t ws_size,
                              hipStream_t stream)
{
  (void)in_sizes; (void)n_in; (void)out_size; (void)ws_size;
  const float* h   = (const float*)d_in[0];
  const float* emb = (const float*)d_in[1];
  const float* lsc = (const float*)d_in[2];
  const int*   tgt = (const int*)d_in[3];
  float* out = (float*)d_out;

  uint8_t* p = (uint8_t*)d_ws;
  auto carve = [&](size_t n)->uint8_t*{
    uint8_t* r = p; p += (n + 255) & ~(size_t)255; return r;
  };
  u8*    emb8   = (u8*)   carve((size_t)V_SIZE * D_DIM);
  u16*   elow16 = (u16*)  carve((size_t)V_SIZE * LOWR * 2);
  float* invn_f = (float*)carve((size_t)V_SIZE * 4);
  float* invn_l = (float*)carve((size_t)V_SIZE * 4);
  float* wlow   = (float*)carve((size_t)V_SIZE * LOWR * 4);
  u8*    h8     = (u8*)   carve((size_t)T_TOK * D_DIM);
  u16*   hlow16 = (u16*)  carve((size_t)T_TOK * LOWR * 2);
  float* invh_f = (float*)carve((size_t)T_TOK * 4);
  float* invh_l = (float*)carve((size_t)T_TOK * 4);
  float* hpart  = (float*)carve((size_t)NCHUNK * 8 * LOWR * 4);
  float* scan   = (float*)carve((size_t)NCHUNK * V_PAD * 4);
  uint32* ghist = (uint32*)carve((size_t)NCHUNK * 2048 * 4);
  int*   topidx = (int*)  carve((size_t)NCHUNK * NCAND * 4);
  float* invc_f = (float*)carve((size_t)NCHUNK * NCAND * 4);
  float* invc_l = (float*)carve((size_t)NCHUNK * NCAND * 4);
  float* pm     = (float*)carve((size_t)NCHUNK * 32 * CCHUNK * 2 * 4);
  float* pa     = (float*)carve((size_t)NCHUNK * 32 * CCHUNK * 2 * 4);

  prep_kernel<<<dim3(NVB + NCHUNK*8), dim3(256), 0, stream>>>(
      emb, emb8, elow16, invn_f, invn_l, wlow, h, h8, hlow16,
      invh_f, invh_l, hpart, ghist, out);
  scan_kernel<<<dim3(V_PAD / 256), dim3(256), 0, stream>>>(wlow, invn_l, hpart, scan);
  topk_hist<<<dim3(NCHUNK, 8), dim3(256), 0, stream>>>(scan, ghist);
  topk_select<<<dim3(NCHUNK), dim3(1024), 0, stream>>>(
      scan, ghist, invn_f, invn_l, topidx, invc_f, invc_l);
  gemm_fused<<<dim3(32 * NCHUNK), dim3(256), 0, stream>>>(
      h8, emb8, hlow16, elow16, topidx, invh_f, invc_f, invh_l, invc_l, tgt, lsc, pm, pa);
  merge_loss<<<dim3(NCHUNK * 4), dim3(256), 0, stream>>>(
      h, emb, tgt, invh_f, invh_l, invn_f, invn_l, pm, pa, lsc, out);
}